// Round 1
// baseline (383.061 us; speedup 1.0000x reference)
//
#include <hip/hip_runtime.h>

#define SEQ_LEN 16384
#define DIM 128
#define NH 256
#define NB 32
#define TOPK 8
#define RPG 8   // rows per group (one group = 8 node rows, 2 rows per wave in phase B)

// ---------------------------------------------------------------------------
// Kernel 1: penalty[n] = mean over batch of mask[:, n].
// Reduction order replicates the previous kernel's xor-butterfly tree exactly
// (pairwise halving 16,8,4,2,1) so results stay bitwise identical (absmax==0).
// Reads are coalesced: for fixed b, consecutive threads read consecutive n.
// ---------------------------------------------------------------------------
__global__ __launch_bounds__(256)
void penalty_kernel(const float* __restrict__ mask, float* __restrict__ pen) {
    const int n = blockIdx.x * 256 + threadIdx.x;
    float t[NB];
    #pragma unroll
    for (int b = 0; b < NB; ++b) t[b] = mask[(size_t)b * SEQ_LEN + n];
    #pragma unroll
    for (int off = 16; off >= 1; off >>= 1) {
        #pragma unroll
        for (int i = 0; i < off; ++i) t[i] += t[i + off];
    }
    pen[n] = t[0] * (1.0f / NB);
}

// ---------------------------------------------------------------------------
// Kernel 2: fused sim -> relu -> *penalty -> softmax stats -> top-8 -> threshold.
// Block = 256 threads (4 waves). Thread t register-caches hyper row t.
// Groups of 8 node rows; double-buffered LDS exchange => ONE barrier per group.
// Phase B: wave wv owns rows r0+2wv, r0+2wv+1, processed interleaved for ILP.
// ---------------------------------------------------------------------------
__global__ __launch_bounds__(256, 2)
void hyper_kernel(const float* __restrict__ pen, const float* __restrict__ node,
                  const float* __restrict__ hyper, float* __restrict__ out) {
    const int tid  = threadIdx.x;
    const int lane = tid & 63;
    const int wv   = tid >> 6;
    __shared__ __align__(16) float sv[2][RPG][NH];

    // register-cache this thread's hyperedge row (h == tid): 32 x float4
    float4 hc[DIM / 4];
    {
        const float4* h4 = (const float4*)(hyper + (size_t)tid * DIM);
        #pragma unroll
        for (int i = 0; i < DIM / 4; ++i) hc[i] = h4[i];
    }

    const int ngroups = SEQ_LEN / RPG;    // 2048
    int buf = 0;
    for (int g = blockIdx.x; g < ngroups; g += gridDim.x, buf ^= 1) {
        const int r0 = g * RPG;
        const float4* n4 = (const float4*)(node + (size_t)r0 * DIM); // block-uniform

        float a[RPG];
        #pragma unroll
        for (int j = 0; j < RPG; ++j) a[j] = 0.f;
        #pragma unroll
        for (int i = 0; i < DIM / 4; ++i) {
            const float4 hv = hc[i];
            #pragma unroll
            for (int j = 0; j < RPG; ++j) {
                const float4 x = n4[j * (DIM / 4) + i];
                a[j] = fmaf(x.x, hv.x, a[j]);
                a[j] = fmaf(x.y, hv.y, a[j]);
                a[j] = fmaf(x.z, hv.z, a[j]);
                a[j] = fmaf(x.w, hv.w, a[j]);
            }
        }
        #pragma unroll
        for (int j = 0; j < RPG; ++j) sv[buf][j][tid] = fmaxf(a[j], 0.f);

        // rows owned by this wave; issue the (L2-resident) penalty loads now so
        // their latency overlaps the barrier wait.
        const int rA = r0 + (wv << 1);
        const int rB = rA + 1;
        const float pA = pen[rA];
        const float pB = pen[rB];

        __syncthreads();   // writes(g) -> reads(g). Reuse of sv[buf] by group
                           // g+2 is fenced by group g+1's barrier (dbl-buffer).

        // -------- Phase B: two rows per wave, interleaved; h = 4*lane + j ----
        const float4 vA = *(const float4*)&sv[buf][(wv << 1) + 0][lane << 2];
        const float4 vB = *(const float4*)&sv[buf][(wv << 1) + 1][lane << 2];
        const float bA0 = vA.x * pA, bA1 = vA.y * pA, bA2 = vA.z * pA, bA3 = vA.w * pA;
        const float bB0 = vB.x * pB, bB1 = vB.y * pB, bB2 = vB.z * pB, bB3 = vB.w * pB;

        // row max (stable softmax, same op order as before)
        float mA = fmaxf(fmaxf(bA0, bA1), fmaxf(bA2, bA3));
        float mB = fmaxf(fmaxf(bB0, bB1), fmaxf(bB2, bB3));
        #pragma unroll
        for (int off = 32; off >= 1; off >>= 1) {
            mA = fmaxf(mA, __shfl_xor(mA, off, 64));
            mB = fmaxf(mB, __shfl_xor(mB, off, 64));
        }

        const float eA0 = expf(bA0 - mA), eA1 = expf(bA1 - mA);
        const float eA2 = expf(bA2 - mA), eA3 = expf(bA3 - mA);
        const float eB0 = expf(bB0 - mB), eB1 = expf(bB1 - mB);
        const float eB2 = expf(bB2 - mB), eB3 = expf(bB3 - mB);
        float zA = eA0 + eA1 + eA2 + eA3;
        float zB = eB0 + eB1 + eB2 + eB3;
        #pragma unroll
        for (int off = 32; off >= 1; off >>= 1) {
            zA += __shfl_xor(zA, off, 64);
            zB += __shfl_xor(zB, off, 64);
        }

        // binary search on float bit patterns (all v >= 0, bits monotone):
        // t = max threshold with count(v >= t) >= 8. Two rows interleaved.
        const unsigned uA0 = __float_as_uint(bA0), uA1 = __float_as_uint(bA1);
        const unsigned uA2 = __float_as_uint(bA2), uA3 = __float_as_uint(bA3);
        const unsigned uB0 = __float_as_uint(bB0), uB1 = __float_as_uint(bB1);
        const unsigned uB2 = __float_as_uint(bB2), uB3 = __float_as_uint(bB3);
        unsigned tA = 0u, tB = 0u;
        for (int bit = 30; bit >= 0; --bit) {
            const unsigned cA = tA | (1u << bit);
            const unsigned cB = tB | (1u << bit);
            const int ca = __popcll(__ballot(uA0 >= cA)) + __popcll(__ballot(uA1 >= cA))
                         + __popcll(__ballot(uA2 >= cA)) + __popcll(__ballot(uA3 >= cA));
            const int cb = __popcll(__ballot(uB0 >= cB)) + __popcll(__ballot(uB1 >= cB))
                         + __popcll(__ballot(uB2 >= cB)) + __popcll(__ballot(uB3 >= cB));
            if (ca >= TOPK) tA = cA;
            if (cb >= TOPK) tB = cB;
        }

        // tie resolution: lowest h index first among equal values (h-major rank)
        const unsigned long long lt = (1ull << lane) - 1ull;

        const int cgtA = __popcll(__ballot(uA0 > tA)) + __popcll(__ballot(uA1 > tA))
                       + __popcll(__ballot(uA2 > tA)) + __popcll(__ballot(uA3 > tA));
        const int needA = TOPK - cgtA;
        const unsigned long long qA0 = __ballot(uA0 == tA), qA1 = __ballot(uA1 == tA);
        const unsigned long long qA2 = __ballot(uA2 == tA), qA3 = __ballot(uA3 == tA);
        const int baseA = __popcll(qA0 & lt) + __popcll(qA1 & lt)
                        + __popcll(qA2 & lt) + __popcll(qA3 & lt);
        const int rkA0 = baseA;
        const int rkA1 = rkA0 + (uA0 == tA ? 1 : 0);
        const int rkA2 = rkA1 + (uA1 == tA ? 1 : 0);
        const int rkA3 = rkA2 + (uA2 == tA ? 1 : 0);

        const int cgtB = __popcll(__ballot(uB0 > tB)) + __popcll(__ballot(uB1 > tB))
                       + __popcll(__ballot(uB2 > tB)) + __popcll(__ballot(uB3 > tB));
        const int needB = TOPK - cgtB;
        const unsigned long long qB0 = __ballot(uB0 == tB), qB1 = __ballot(uB1 == tB);
        const unsigned long long qB2 = __ballot(uB2 == tB), qB3 = __ballot(uB3 == tB);
        const int baseB = __popcll(qB0 & lt) + __popcll(qB1 & lt)
                        + __popcll(qB2 & lt) + __popcll(qB3 & lt);
        const int rkB0 = baseB;
        const int rkB1 = rkB0 + (uB0 == tB ? 1 : 0);
        const int rkB2 = rkB1 + (uB1 == tB ? 1 : 0);
        const int rkB3 = rkB2 + (uB2 == tB ? 1 : 0);

        // threshold: softmax p > 0.001  <=>  e > 0.001 * z
        const float zthA = 0.001f * zA;
        const float zthB = 0.001f * zB;
        const bool sA0 = ((uA0 > tA) || ((uA0 == tA) && rkA0 < needA)) && (eA0 > zthA);
        const bool sA1 = ((uA1 > tA) || ((uA1 == tA) && rkA1 < needA)) && (eA1 > zthA);
        const bool sA2 = ((uA2 > tA) || ((uA2 == tA) && rkA2 < needA)) && (eA2 > zthA);
        const bool sA3 = ((uA3 > tA) || ((uA3 == tA) && rkA3 < needA)) && (eA3 > zthA);
        const bool sB0 = ((uB0 > tB) || ((uB0 == tB) && rkB0 < needB)) && (eB0 > zthB);
        const bool sB1 = ((uB1 > tB) || ((uB1 == tB) && rkB1 < needB)) && (eB1 > zthB);
        const bool sB2 = ((uB2 > tB) || ((uB2 == tB) && rkB2 < needB)) && (eB2 > zthB);
        const bool sB3 = ((uB3 > tB) || ((uB3 == tB) && rkB3 < needB)) && (eB3 > zthB);

        float4 oA, oB;
        oA.x = sA0 ? 1.f : 0.f; oA.y = sA1 ? 1.f : 0.f;
        oA.z = sA2 ? 1.f : 0.f; oA.w = sA3 ? 1.f : 0.f;
        oB.x = sB0 ? 1.f : 0.f; oB.y = sB1 ? 1.f : 0.f;
        oB.z = sB2 ? 1.f : 0.f; oB.w = sB3 ? 1.f : 0.f;
        *(float4*)(out + (size_t)rA * NH + (lane << 2)) = oA;
        *(float4*)(out + (size_t)rB * NH + (lane << 2)) = oB;
    }
}

extern "C" void kernel_launch(void* const* d_in, const int* in_sizes, int n_in,
                              void* d_out, int out_size, void* d_ws, size_t ws_size,
                              hipStream_t stream) {
    // inputs: 0=features (unused), 1=mask [B,SEQ], 2=node_embeds [SEQ,D], 3=hyper_embeds [H,D]
    const float* mask  = (const float*)d_in[1];
    const float* node  = (const float*)d_in[2];
    const float* hyper = (const float*)d_in[3];
    float* out = (float*)d_out;
    float* pen = (float*)d_ws;   // 16384 floats = 64 KB, recomputed every launch

    penalty_kernel<<<SEQ_LEN / 256, 256, 0, stream>>>(mask, pen);
    hyper_kernel<<<512, 256, 0, stream>>>(pen, node, hyper, out);
}

// Round 2
// 365.940 us; speedup vs baseline: 1.0468x; 1.0468x over previous
//
#include <hip/hip_runtime.h>

#define SEQ_LEN 16384
#define DIM 128
#define NH 256
#define NB 32
#define TOPK 8

// ---------------------------------------------------------------------------
// Kernel 1: penalty[n] = mean over batch of mask[:, n].
// Reduction tree replicates the original xor-butterfly pairing exactly
// (verified bitwise: absmax == 0.0 in the previous round). Fully coalesced.
// ---------------------------------------------------------------------------
__global__ __launch_bounds__(256)
void penalty_kernel(const float* __restrict__ mask, float* __restrict__ pen) {
    const int n = blockIdx.x * 256 + threadIdx.x;
    float t[NB];
    #pragma unroll
    for (int b = 0; b < NB; ++b) t[b] = mask[(size_t)b * SEQ_LEN + n];
    #pragma unroll
    for (int off = 16; off >= 1; off >>= 1) {
        #pragma unroll
        for (int i = 0; i < off; ++i) t[i] += t[i + off];
    }
    pen[n] = t[0] * (1.0f / NB);
}

// ---------------------------------------------------------------------------
// Kernel 2: fused sim -> relu -> *penalty -> softmax stats -> top-8 -> threshold.
// Round-0 proven structure: block = 256 threads (4 waves), thread t register-
// caches hyper row t, groups of 4 node rows, wave w owns row w in phase B.
// Only change vs round 0: penalty comes from pen[] via one wave-uniform
// scalar load instead of a 32-lane strided gather + 6-step shuffle reduce.
// ---------------------------------------------------------------------------
__global__ __launch_bounds__(256, 2)
void hyper_kernel(const float* __restrict__ pen, const float* __restrict__ node,
                  const float* __restrict__ hyper, float* __restrict__ out) {
    const int tid  = threadIdx.x;
    const int lane = tid & 63;
    const int wv   = tid >> 6;
    __shared__ __align__(16) float sv[4][NH];

    // register-cache this thread's hyperedge row (h == tid): 32 x float4
    float4 hc[DIM / 4];
    {
        const float4* h4 = (const float4*)(hyper + (size_t)tid * DIM);
        #pragma unroll
        for (int i = 0; i < DIM / 4; ++i) hc[i] = h4[i];
    }

    const int ngroups = SEQ_LEN / 4;
    for (int g = blockIdx.x; g < ngroups; g += gridDim.x) {
        const int r0  = g * 4;
        const int row = r0 + wv;                  // row owned by this wave in Phase B
        const float4* n4 = (const float4*)(node + (size_t)r0 * DIM); // block-uniform

        float a0 = 0.f, a1 = 0.f, a2 = 0.f, a3 = 0.f;
        #pragma unroll
        for (int i = 0; i < DIM / 4; ++i) {
            const float4 hv = hc[i];
            const float4 x0 = n4[i];
            const float4 x1 = n4[(DIM / 4) + i];
            const float4 x2 = n4[2 * (DIM / 4) + i];
            const float4 x3 = n4[3 * (DIM / 4) + i];
            a0 = fmaf(x0.x, hv.x, a0); a0 = fmaf(x0.y, hv.y, a0);
            a0 = fmaf(x0.z, hv.z, a0); a0 = fmaf(x0.w, hv.w, a0);
            a1 = fmaf(x1.x, hv.x, a1); a1 = fmaf(x1.y, hv.y, a1);
            a1 = fmaf(x1.z, hv.z, a1); a1 = fmaf(x1.w, hv.w, a1);
            a2 = fmaf(x2.x, hv.x, a2); a2 = fmaf(x2.y, hv.y, a2);
            a2 = fmaf(x2.z, hv.z, a2); a2 = fmaf(x2.w, hv.w, a2);
            a3 = fmaf(x3.x, hv.x, a3); a3 = fmaf(x3.y, hv.y, a3);
            a3 = fmaf(x3.z, hv.z, a3); a3 = fmaf(x3.w, hv.w, a3);
        }

        __syncthreads();                 // protect sv reuse from previous group
        sv[0][tid] = fmaxf(a0, 0.f);     // relu(alpha*sim), unscaled
        sv[1][tid] = fmaxf(a1, 0.f);
        sv[2][tid] = fmaxf(a2, 0.f);
        sv[3][tid] = fmaxf(a3, 0.f);
        // wave-uniform penalty load (s_load); latency overlaps the barrier wait
        const float p = pen[row];
        __syncthreads();

        // -------- Phase B: wave wv handles `row`; h = 4*lane + j --------
        const float4 vvv = *(const float4*)&sv[wv][lane << 2];
        const float b0 = vvv.x * p, b1 = vvv.y * p;
        const float b2 = vvv.z * p, b3 = vvv.w * p;

        // row max (stable softmax, matches jax.nn.softmax)
        float m = fmaxf(fmaxf(b0, b1), fmaxf(b2, b3));
        #pragma unroll
        for (int off = 32; off >= 1; off >>= 1) m = fmaxf(m, __shfl_xor(m, off, 64));

        const float e0 = expf(b0 - m), e1 = expf(b1 - m);
        const float e2 = expf(b2 - m), e3 = expf(b3 - m);
        float z = e0 + e1 + e2 + e3;
        #pragma unroll
        for (int off = 32; off >= 1; off >>= 1) z += __shfl_xor(z, off, 64);

        // binary search on float bit patterns (all v >= 0 so bits are monotone)
        // for t = bits(8th-largest value): max t with count(v >= t) >= 8
        const unsigned u0 = __float_as_uint(b0), u1 = __float_as_uint(b1);
        const unsigned u2 = __float_as_uint(b2), u3 = __float_as_uint(b3);
        unsigned t = 0u;
        for (int bit = 30; bit >= 0; --bit) {
            const unsigned cand = t | (1u << bit);
            const int c = __popcll(__ballot(u0 >= cand)) + __popcll(__ballot(u1 >= cand))
                        + __popcll(__ballot(u2 >= cand)) + __popcll(__ballot(u3 >= cand));
            if (c >= TOPK) t = cand;
        }
        // tie resolution: jax.lax.top_k takes lowest indices first among equal values
        const int cgt = __popcll(__ballot(u0 > t)) + __popcll(__ballot(u1 > t))
                      + __popcll(__ballot(u2 > t)) + __popcll(__ballot(u3 > t));
        const int need = TOPK - cgt;
        const unsigned long long q0 = __ballot(u0 == t), q1 = __ballot(u1 == t);
        const unsigned long long q2 = __ballot(u2 == t), q3 = __ballot(u3 == t);
        const unsigned long long lt = (1ull << lane) - 1ull; // lanes below (h-major order)
        const int base = __popcll(q0 & lt) + __popcll(q1 & lt)
                       + __popcll(q2 & lt) + __popcll(q3 & lt);
        const int rk0 = base;
        const int rk1 = rk0 + (u0 == t ? 1 : 0);
        const int rk2 = rk1 + (u1 == t ? 1 : 0);
        const int rk3 = rk2 + (u2 == t ? 1 : 0);

        // threshold: softmax p > 0.001  <=>  e > 0.001 * z
        const float zth = 0.001f * z;
        const bool s0 = ((u0 > t) || ((u0 == t) && rk0 < need)) && (e0 > zth);
        const bool s1 = ((u1 > t) || ((u1 == t) && rk1 < need)) && (e1 > zth);
        const bool s2 = ((u2 > t) || ((u2 == t) && rk2 < need)) && (e2 > zth);
        const bool s3 = ((u3 > t) || ((u3 == t) && rk3 < need)) && (e3 > zth);

        float4 o;
        o.x = s0 ? 1.f : 0.f;
        o.y = s1 ? 1.f : 0.f;
        o.z = s2 ? 1.f : 0.f;
        o.w = s3 ? 1.f : 0.f;
        *(float4*)(out + (size_t)row * NH + (lane << 2)) = o;
    }
}

extern "C" void kernel_launch(void* const* d_in, const int* in_sizes, int n_in,
                              void* d_out, int out_size, void* d_ws, size_t ws_size,
                              hipStream_t stream) {
    // inputs: 0=features (unused), 1=mask [B,SEQ], 2=node_embeds [SEQ,D], 3=hyper_embeds [H,D]
    const float* mask  = (const float*)d_in[1];
    const float* node  = (const float*)d_in[2];
    const float* hyper = (const float*)d_in[3];
    float* out = (float*)d_out;
    float* pen = (float*)d_ws;   // 16384 floats = 64 KB, recomputed every launch

    penalty_kernel<<<SEQ_LEN / 256, 256, 0, stream>>>(mask, pen);
    hyper_kernel<<<512, 256, 0, stream>>>(pen, node, hyper, out);
}